// Round 7
// baseline (2455.817 us; speedup 1.0000x reference)
//
#include <hip/hip_runtime.h>

typedef __attribute__((ext_vector_type(8))) short short8v;
typedef __attribute__((ext_vector_type(4))) float f32x4;

#define NB 1024
#define NS 200
#define ND 512
#define NG 1536
#define NM 204800   // NB*NS
#define NFF 256

#define GRU_P 4     // blocks per group (each owns 128 h-cols)
#define GRU_G 64    // groups (each owns 16 batches)

__device__ __forceinline__ float bf2f(unsigned short u){
  union { unsigned u; float f; } v; v.u = ((unsigned)u) << 16; return v.f;
}
__device__ __forceinline__ unsigned short f2bf(float f){
  union { float f; unsigned u; } v; v.f = f;
  unsigned r = v.u + 0x7fffu + ((v.u >> 16) & 1u);
  return (unsigned short)(r >> 16);
}
__device__ __forceinline__ float sigm(float x){ return 1.f / (1.f + __expf(-x)); }
__device__ __forceinline__ float tanhfast(float x){ return 1.f - 2.f / (1.f + __expf(2.f * x)); }

// ---------------- pack W (N x K, row-major, f32) into MFMA B-frag order ----------------
__global__ void k_prepack(const float* __restrict__ W, unsigned short* __restrict__ out,
                          int ld, int coloff, int ntiles){
  int gid = blockIdx.x * 256 + threadIdx.x;
  if (gid >= ntiles * 1024) return;
  int ntile = gid >> 10; int rem = gid & 1023;
  int kk = rem >> 6; int lane = rem & 63;
  int c = ntile * 16 + (lane & 15);
  int k0 = kk * 32 + (lane >> 4) * 8;
  const float* s = W + (size_t)c * ld + coloff + k0;
  uint4 v;
  v.x = (unsigned)f2bf(s[0]) | ((unsigned)f2bf(s[1]) << 16);
  v.y = (unsigned)f2bf(s[2]) | ((unsigned)f2bf(s[3]) << 16);
  v.z = (unsigned)f2bf(s[4]) | ((unsigned)f2bf(s[5]) << 16);
  v.w = (unsigned)f2bf(s[6]) | ((unsigned)f2bf(s[7]) << 16);
  *(uint4*)(out + (size_t)gid * 8) = v;
}

// ---------------- tvec[b][f] = b_fc[f] + sum_d target[b][d] * W_fc[f][512+d] ----------------
__global__ void k_tvec(const float* __restrict__ target, const float* __restrict__ Wfc,
                       const float* __restrict__ bfc, float* __restrict__ tvec){
  __shared__ float tg[4][ND];
  int bb = blockIdx.x;
  int tid = threadIdx.x;
  for (int idx = tid; idx < 4 * ND; idx += 256){
    int j = idx >> 9, d = idx & 511;
    tg[j][d] = target[(size_t)(bb * 4 + j) * ND + d];
  }
  __syncthreads();
  const float* wrow = Wfc + (size_t)tid * 1024 + 512;
  float a0 = 0, a1 = 0, a2 = 0, a3 = 0;
  for (int d = 0; d < ND; ++d){
    float wv = wrow[d];
    a0 += tg[0][d] * wv; a1 += tg[1][d] * wv; a2 += tg[2][d] * wv; a3 += tg[3][d] * wv;
  }
  float bias = bfc[tid];
  tvec[(size_t)(bb * 4 + 0) * NFF + tid] = a0 + bias;
  tvec[(size_t)(bb * 4 + 1) * NFF + tid] = a1 + bias;
  tvec[(size_t)(bb * 4 + 2) * NFF + tid] = a2 + bias;
  tvec[(size_t)(bb * 4 + 3) * NFF + tid] = a3 + bias;
}

// ---------------- gx = history(f32) @ W_ih^T + b_ih, output bf16 (NM x 1536) ----------------
__global__ __launch_bounds__(256) void k_gemm_gx(const float* __restrict__ Af,
                                                 const unsigned short* __restrict__ Bpk,
                                                 const float* __restrict__ bih,
                                                 unsigned short* __restrict__ gx){
  __shared__ unsigned short As[128 * 64];
  int tid = threadIdx.x; int lane = tid & 63; int wid = tid >> 6;
  int wm = wid >> 1, wn = wid & 1;
  int Nb = blockIdx.x, Mb = blockIdx.y;
  const float* Abase = Af + (size_t)Mb * 128 * ND;
  const short8v* Bp = (const short8v*)Bpk;
  f32x4 acc[4][4];
  #pragma unroll
  for (int i = 0; i < 4; ++i)
    #pragma unroll
    for (int j = 0; j < 4; ++j) acc[i][j] = (f32x4){0.f, 0.f, 0.f, 0.f};

  for (int kc = 0; kc < 8; ++kc){
    __syncthreads();
    #pragma unroll
    for (int pass = 0; pass < 4; ++pass){
      int idx = pass * 256 + tid; int r = idx >> 3, ch = idx & 7;
      const float* src = Abase + (size_t)r * ND + kc * 64 + ch * 8;
      float4 f0 = *(const float4*)src;
      float4 f1 = *(const float4*)(src + 4);
      uint4 v;
      v.x = (unsigned)f2bf(f0.x) | ((unsigned)f2bf(f0.y) << 16);
      v.y = (unsigned)f2bf(f0.z) | ((unsigned)f2bf(f0.w) << 16);
      v.z = (unsigned)f2bf(f1.x) | ((unsigned)f2bf(f1.y) << 16);
      v.w = (unsigned)f2bf(f1.z) | ((unsigned)f2bf(f1.w) << 16);
      *(uint4*)&As[r * 64 + ch * 8] = v;
    }
    __syncthreads();
    #pragma unroll
    for (int i = 0; i < 2; ++i){
      short8v a[4];
      #pragma unroll
      for (int mt = 0; mt < 4; ++mt)
        a[mt] = *(const short8v*)&As[(wm * 64 + mt * 16 + (lane & 15)) * 64 + i * 32 + (lane >> 4) * 8];
      #pragma unroll
      for (int nt = 0; nt < 4; ++nt){
        short8v b = Bp[((size_t)(Nb * 8 + wn * 4 + nt) * 16 + (kc * 2 + i)) * 64 + lane];
        #pragma unroll
        for (int mt = 0; mt < 4; ++mt)
          acc[mt][nt] = __builtin_amdgcn_mfma_f32_16x16x32_bf16(a[mt], b, acc[mt][nt], 0, 0, 0);
      }
    }
  }
  #pragma unroll
  for (int mt = 0; mt < 4; ++mt){
    #pragma unroll
    for (int nt = 0; nt < 4; ++nt){
      int gcol = Nb * 128 + wn * 64 + nt * 16 + (lane & 15);
      float bv = bih[gcol];
      #pragma unroll
      for (int r = 0; r < 4; ++r){
        int grow = Mb * 128 + wm * 64 + mt * 16 + (lane >> 4) * 4 + r;
        gx[(size_t)grow * NG + gcol] = f2bf(acc[mt][nt][r] + bv);
      }
    }
  }
}

// ---------------- GRU recurrence v6 ----------------
// 64 groups x 4 blocks; W_hh slice resident in unified VGPR/AGPR file.
// Proven agent-scope relaxed-atomic exchange (round-4 protocol), with:
//   - monotonic per-wave flag counters (hot lines, no per-step cold flags)
//   - single-wave (wave 0) flag polling + barrier broadcast (kills poll storm)
//   - gout stores issued after the flag store (shorter pre-flag chain)
__global__ __launch_bounds__(512, 1) void k_gru6(const unsigned short* __restrict__ gx,
                                                 const unsigned short* __restrict__ Wpk,
                                                 const float* __restrict__ bhh,
                                                 unsigned short* __restrict__ gout,
                                                 unsigned short* __restrict__ hx,   // [2][1024*512] bf16
                                                 int* __restrict__ flags){          // [GRU_G*32] monotonic
  __shared__ unsigned short hbuf[2][16 * 512];   // [parity][16 k-frags of 1KB]
  int tid = threadIdx.x; int lane = tid & 63; int nh = tid >> 6;   // wave 0..7
  int bid = blockIdx.x; int g = bid & 63; int s = bid >> 6;        // group, slice
  int colg = lane & 15;
  int rowg = lane >> 4;
  int c_h = s * 128 + nh * 16 + colg;   // this lane's h column
  int b0 = g * 16;                      // group batch base
  int* gfl = flags + g * 32;            // this group's 32 wave-flags

  for (int i = tid; i < 16 * 512; i += 512) hbuf[0][i] = 0;

  // resident W_hh B-fragments: 3 gate tiles x 16 k-frags = 192 regs
  short8v wf[3][16];
  const short8v* Wp = (const short8v*)Wpk;
  #pragma unroll
  for (int gg = 0; gg < 3; ++gg){
    int ntile = gg * 32 + s * 8 + nh;
    #pragma unroll
    for (int kk = 0; kk < 16; ++kk)
      wf[gg][kk] = Wp[((size_t)ntile * 16 + kk) * 64 + lane];
  }
  float bR = bhh[c_h], bZ = bhh[512 + c_h], bN = bhh[1024 + c_h];
  float hreg[4] = {0.f, 0.f, 0.f, 0.f};

  // preload gx for t=0
  unsigned short cxr[4], cxz[4], cxn[4];
  #pragma unroll
  for (int r = 0; r < 4; ++r){
    const unsigned short* gp = gx + ((size_t)(b0 + rowg * 4 + r) * NS + 0) * NG;
    cxr[r] = gp[c_h]; cxz[r] = gp[512 + c_h]; cxn[r] = gp[1024 + c_h];
  }
  __syncthreads();

  #pragma unroll 1
  for (int t = 0; t < NS; ++t){
    int par = t & 1;
    const unsigned short* hr = hbuf[par];
    // prefetch gx for t+1 (latency hidden under MFMA + sync)
    unsigned short nxr[4], nxz[4], nxn[4];
    if (t + 1 < NS){
      #pragma unroll
      for (int r = 0; r < 4; ++r){
        const unsigned short* gp = gx + ((size_t)(b0 + rowg * 4 + r) * NS + (t + 1)) * NG;
        nxr[r] = gp[c_h]; nxz[r] = gp[512 + c_h]; nxn[r] = gp[1024 + c_h];
      }
    }
    // gh = h @ Whh_slice^T
    f32x4 acc0 = (f32x4){0.f,0.f,0.f,0.f}, acc1 = acc0, acc2 = acc0;
    #pragma unroll
    for (int kc = 0; kc < 16; ++kc){
      short8v a = *(const short8v*)&hr[kc * 512 + lane * 8];
      acc0 = __builtin_amdgcn_mfma_f32_16x16x32_bf16(a, wf[0][kc], acc0, 0, 0, 0);
      acc1 = __builtin_amdgcn_mfma_f32_16x16x32_bf16(a, wf[1][kc], acc1, 0, 0, 0);
      acc2 = __builtin_amdgcn_mfma_f32_16x16x32_bf16(a, wf[2][kc], acc2, 0, 0, 0);
    }
    // activations; h kept in f32 regs across steps
    unsigned short hnew[4];
    #pragma unroll
    for (int r = 0; r < 4; ++r){
      float rr = sigm(bf2f(cxr[r]) + acc0[r] + bR);
      float zz = sigm(bf2f(cxz[r]) + acc1[r] + bZ);
      float nn = tanhfast(bf2f(cxn[r]) + rr * (acc2[r] + bN));
      float h = nn + zz * (hreg[r] - nn);
      hreg[r] = h;
      hnew[r] = f2bf(h);
    }

    if (t + 1 < NS){
      unsigned short* hxp = hx + (size_t)par * (1024 * 512);
      // paired 4B h-slice stores (lane colg even stores [c, c+1])
      #pragma unroll
      for (int r = 0; r < 4; ++r){
        unsigned hv = (unsigned)hnew[r];
        unsigned ov = (unsigned)(unsigned short)__shfl_xor((int)hv, 1, 64);
        if (!(colg & 1)){
          unsigned v = hv | (ov << 16);
          __hip_atomic_store((unsigned*)(hxp + (size_t)(b0 + rowg * 4 + r) * 512 + c_h), v,
                             __ATOMIC_RELAXED, __HIP_MEMORY_SCOPE_AGENT);
        }
      }
      // per-wave drain: this wave's hx stores complete at the coherence point
      asm volatile("s_waitcnt vmcnt(0)" ::: "memory");
      // per-wave monotonic flag
      if (lane == 0)
        __hip_atomic_store(&gfl[s * 8 + nh], t + 1, __ATOMIC_RELAXED, __HIP_MEMORY_SCOPE_AGENT);
      // gout stores ride behind the flag (no ordering needed; drained by next barrier)
      #pragma unroll
      for (int r = 0; r < 4; ++r)
        gout[((size_t)(b0 + rowg * 4 + r) * NS + t) * ND + c_h] = hnew[r];
      // wave 0 polls all 32 wave-flags; others wait at the barrier
      if (nh == 0){
        int need = t + 1; int fv;
        do {
          fv = (lane < 32) ? __hip_atomic_load(&gfl[lane], __ATOMIC_RELAXED, __HIP_MEMORY_SCOPE_AGENT) : need;
        } while (!__all(fv >= need));
      }
      __syncthreads();   // B2: poll result broadcast
      // reload full h_t into other-parity LDS in MFMA A-frag layout
      unsigned short* hw = hbuf[par ^ 1];
      const unsigned long long* hxq = (const unsigned long long*)hxp;
      #pragma unroll
      for (int q = 0; q < 2; ++q){
        int kc = q * 8 + nh;
        size_t base = (size_t)(b0 + (lane & 15)) * 128 + kc * 8 + (lane >> 4) * 2;
        unsigned long long u0 = __hip_atomic_load(&hxq[base],     __ATOMIC_RELAXED, __HIP_MEMORY_SCOPE_AGENT);
        unsigned long long u1 = __hip_atomic_load(&hxq[base + 1], __ATOMIC_RELAXED, __HIP_MEMORY_SCOPE_AGENT);
        unsigned long long tmp[2] = {u0, u1};
        *(uint4*)&hw[kc * 512 + lane * 8] = *(const uint4*)tmp;
      }
      __syncthreads();   // B3: LDS h ready for next step
    } else {
      #pragma unroll
      for (int r = 0; r < 4; ++r)
        gout[((size_t)(b0 + rowg * 4 + r) * NS + t) * ND + c_h] = hnew[r];
    }
    #pragma unroll
    for (int r = 0; r < 4; ++r){ cxr[r] = nxr[r]; cxz[r] = nxz[r]; cxn[r] = nxn[r]; }
  }
}

// ---------------- pre/GELU/scores fused GEMM: (NM x 512) @ Wg^T (256) ----------------
__global__ __launch_bounds__(512) void k_gemm_s4(const unsigned short* __restrict__ A,
                                                 const unsigned short* __restrict__ Bpk,
                                                 const float* __restrict__ tvec,
                                                 const float* __restrict__ Wsc,
                                                 const float* __restrict__ bsc,
                                                 float* __restrict__ scores){
  __shared__ unsigned short As[128 * 64];
  __shared__ float spart[4][128];
  int tid = threadIdx.x; int lane = tid & 63; int wid = tid >> 6;
  int wm = wid >> 2, wn = wid & 3;
  int Mb = blockIdx.x;
  const unsigned short* Abase = A + (size_t)Mb * 128 * ND;
  const short8v* Bp = (const short8v*)Bpk;
  f32x4 acc[4][4];
  #pragma unroll
  for (int i = 0; i < 4; ++i)
    #pragma unroll
    for (int j = 0; j < 4; ++j) acc[i][j] = (f32x4){0.f, 0.f, 0.f, 0.f};

  for (int kc = 0; kc < 8; ++kc){
    __syncthreads();
    #pragma unroll
    for (int pass = 0; pass < 2; ++pass){
      int idx = pass * 512 + tid; int r = idx >> 3, ch = idx & 7;
      uint4 v = *(const uint4*)(Abase + (size_t)r * ND + kc * 64 + ch * 8);
      *(uint4*)&As[r * 64 + ch * 8] = v;
    }
    __syncthreads();
    #pragma unroll
    for (int i = 0; i < 2; ++i){
      short8v a[4];
      #pragma unroll
      for (int mt = 0; mt < 4; ++mt)
        a[mt] = *(const short8v*)&As[(wm * 64 + mt * 16 + (lane & 15)) * 64 + i * 32 + (lane >> 4) * 8];
      #pragma unroll
      for (int nt = 0; nt < 4; ++nt){
        short8v b = Bp[((size_t)(wn * 4 + nt) * 16 + (kc * 2 + i)) * 64 + lane];
        #pragma unroll
        for (int mt = 0; mt < 4; ++mt)
          acc[mt][nt] = __builtin_amdgcn_mfma_f32_16x16x32_bf16(a[mt], b, acc[mt][nt], 0, 0, 0);
      }
    }
  }
  #pragma unroll
  for (int mt = 0; mt < 4; ++mt){
    #pragma unroll
    for (int r = 0; r < 4; ++r){
      int rowl = wm * 64 + mt * 16 + (lane >> 4) * 4 + r;
      unsigned grow = (unsigned)(Mb * 128 + rowl);
      unsigned bidx = grow / 200u;
      float rowsum = 0.f;
      #pragma unroll
      for (int nt = 0; nt < 4; ++nt){
        int gcol = wn * 64 + nt * 16 + (lane & 15);
        float pre = acc[mt][nt][r] + tvec[(size_t)bidx * NFF + gcol];
        float g = 0.5f * pre * (1.f + erff(pre * 0.70710678118654752f));
        rowsum += g * Wsc[gcol];
      }
      rowsum += __shfl_xor(rowsum, 1, 64);
      rowsum += __shfl_xor(rowsum, 2, 64);
      rowsum += __shfl_xor(rowsum, 4, 64);
      rowsum += __shfl_xor(rowsum, 8, 64);
      if ((lane & 15) == 0) spart[wn][rowl] = rowsum;
    }
  }
  __syncthreads();
  if (tid < 128){
    float s = spart[0][tid] + spart[1][tid] + spart[2][tid] + spart[3][tid] + bsc[0];
    scores[(size_t)Mb * 128 + tid] = s;
  }
}

// ---------------- softmax over S + weighted pool + concat output ----------------
__global__ void k_out(const float* __restrict__ scores, const unsigned short* __restrict__ gout,
                      const float* __restrict__ target, float* __restrict__ out){
  int b = blockIdx.x; int tid = threadIdx.x;
  __shared__ float sw[NS];
  __shared__ float red[4];
  float v = (tid < NS) ? scores[(size_t)b * NS + tid] : -3.0e38f;
  float m = v;
  #pragma unroll
  for (int off = 32; off >= 1; off >>= 1) m = fmaxf(m, __shfl_xor(m, off, 64));
  if ((tid & 63) == 0) red[tid >> 6] = m;
  __syncthreads();
  m = fmaxf(fmaxf(red[0], red[1]), fmaxf(red[2], red[3]));
  float e = (tid < NS) ? __expf(v - m) : 0.f;
  if (tid < NS) sw[tid] = e;
  float su = e;
  #pragma unroll
  for (int off = 32; off >= 1; off >>= 1) su += __shfl_xor(su, off, 64);
  __syncthreads();
  if ((tid & 63) == 0) red[tid >> 6] = su;
  __syncthreads();
  float inv = 1.f / (red[0] + red[1] + red[2] + red[3]);
  int d0 = tid * 2;
  float a0 = 0.f, a1 = 0.f;
  const unsigned short* gbase = gout + (size_t)b * NS * ND + d0;
  for (int s = 0; s < NS; ++s){
    unsigned u = *(const unsigned*)(gbase + (size_t)s * ND);
    float wgt = sw[s];
    a0 += wgt * bf2f((unsigned short)(u & 0xffffu));
    a1 += wgt * bf2f((unsigned short)(u >> 16));
  }
  out[(size_t)b * 1024 + d0] = a0 * inv;
  out[(size_t)b * 1024 + d0 + 1] = a1 * inv;
  float2 tv = *(const float2*)(target + (size_t)b * ND + d0);
  out[(size_t)b * 1024 + 512 + d0] = tv.x;
  out[(size_t)b * 1024 + 512 + d0 + 1] = tv.y;
}

extern "C" void kernel_launch(void* const* d_in, const int* in_sizes, int n_in,
                              void* d_out, int out_size, void* d_ws, size_t ws_size,
                              hipStream_t stream) {
  const float* target  = (const float*)d_in[0];
  const float* history = (const float*)d_in[1];
  const float* W_ih    = (const float*)d_in[2];
  const float* W_hh    = (const float*)d_in[3];
  const float* b_ih    = (const float*)d_in[4];
  const float* b_hh    = (const float*)d_in[5];
  const float* W_fc    = (const float*)d_in[6];
  const float* b_fc    = (const float*)d_in[7];
  const float* W_sc    = (const float*)d_in[8];
  const float* b_sc    = (const float*)d_in[9];

  char* ws = (char*)d_ws;
  size_t off = 0;
  unsigned short* gx     = (unsigned short*)(ws + off); off += 629145600ull;  // NM*1536 bf16
  unsigned short* gout   = (unsigned short*)(ws + off); off += 209715200ull;  // NM*512 bf16
  unsigned short* wih_pk = (unsigned short*)(ws + off); off += 1572864ull;
  unsigned short* whh_pk = (unsigned short*)(ws + off); off += 1572864ull;
  unsigned short* wg_pk  = (unsigned short*)(ws + off); off += 262144ull;
  float*          tvec   = (float*)(ws + off);          off += 1048576ull;
  float*          scores = (float*)(ws + off);          off += 819200ull;
  unsigned short* hx     = (unsigned short*)(ws + off); off += 2097152ull;    // [2][1024*512] bf16
  int*            flags  = (int*)(ws + off);             off += 8192ull;       // [64*32] monotonic
  if (ws_size < off) return;
  float* outp = (float*)d_out;

  (void)hipMemsetAsync(flags, 0, GRU_G * 32 * sizeof(int), stream);
  k_prepack<<<384, 256, 0, stream>>>(W_ih, wih_pk, 512, 0, 96);
  k_prepack<<<384, 256, 0, stream>>>(W_hh, whh_pk, 512, 0, 96);
  k_prepack<<<64, 256, 0, stream>>>(W_fc, wg_pk, 1024, 0, 16);
  k_tvec<<<256, 256, 0, stream>>>(target, W_fc, b_fc, tvec);
  k_gemm_gx<<<dim3(12, 1600), 256, 0, stream>>>(history, wih_pk, b_ih, gx);
  k_gru6<<<256, 512, 0, stream>>>(gx, whh_pk, b_hh, gout, hx, flags);
  k_gemm_s4<<<1600, 512, 0, stream>>>(gout, wg_pk, tvec, W_sc, b_sc, scores);
  k_out<<<1024, 256, 0, stream>>>(scores, gout, target, outp);
}

// Round 8
// 2041.359 us; speedup vs baseline: 1.2030x; 1.2030x over previous
//
#include <hip/hip_runtime.h>

typedef __attribute__((ext_vector_type(8))) short short8v;
typedef __attribute__((ext_vector_type(4))) float f32x4;

#define NB 1024
#define NS 200
#define ND 512
#define NG 1536
#define NM 204800   // NB*NS
#define NFF 256

#define GRU_P 4     // blocks per group (each owns 128 h-cols)
#define GRU_G 64    // groups (each owns 16 batches)

__device__ __forceinline__ float bf2f(unsigned short u){
  union { unsigned u; float f; } v; v.u = ((unsigned)u) << 16; return v.f;
}
__device__ __forceinline__ unsigned short f2bf(float f){
  union { float f; unsigned u; } v; v.f = f;
  unsigned r = v.u + 0x7fffu + ((v.u >> 16) & 1u);
  return (unsigned short)(r >> 16);
}
__device__ __forceinline__ float sigm(float x){ return 1.f / (1.f + __expf(-x)); }
__device__ __forceinline__ float tanhfast(float x){ return 1.f - 2.f / (1.f + __expf(2.f * x)); }

// ---------------- pack W (N x K, row-major, f32) into MFMA B-frag order ----------------
__global__ void k_prepack(const float* __restrict__ W, unsigned short* __restrict__ out,
                          int ld, int coloff, int ntiles){
  int gid = blockIdx.x * 256 + threadIdx.x;
  if (gid >= ntiles * 1024) return;
  int ntile = gid >> 10; int rem = gid & 1023;
  int kk = rem >> 6; int lane = rem & 63;
  int c = ntile * 16 + (lane & 15);
  int k0 = kk * 32 + (lane >> 4) * 8;
  const float* s = W + (size_t)c * ld + coloff + k0;
  uint4 v;
  v.x = (unsigned)f2bf(s[0]) | ((unsigned)f2bf(s[1]) << 16);
  v.y = (unsigned)f2bf(s[2]) | ((unsigned)f2bf(s[3]) << 16);
  v.z = (unsigned)f2bf(s[4]) | ((unsigned)f2bf(s[5]) << 16);
  v.w = (unsigned)f2bf(s[6]) | ((unsigned)f2bf(s[7]) << 16);
  *(uint4*)(out + (size_t)gid * 8) = v;
}

// ---------------- tvec[b][f] = b_fc[f] + sum_d target[b][d] * W_fc[f][512+d] ----------------
__global__ void k_tvec(const float* __restrict__ target, const float* __restrict__ Wfc,
                       const float* __restrict__ bfc, float* __restrict__ tvec){
  __shared__ float tg[4][ND];
  int bb = blockIdx.x;
  int tid = threadIdx.x;
  for (int idx = tid; idx < 4 * ND; idx += 256){
    int j = idx >> 9, d = idx & 511;
    tg[j][d] = target[(size_t)(bb * 4 + j) * ND + d];
  }
  __syncthreads();
  const float* wrow = Wfc + (size_t)tid * 1024 + 512;
  float a0 = 0, a1 = 0, a2 = 0, a3 = 0;
  for (int d = 0; d < ND; ++d){
    float wv = wrow[d];
    a0 += tg[0][d] * wv; a1 += tg[1][d] * wv; a2 += tg[2][d] * wv; a3 += tg[3][d] * wv;
  }
  float bias = bfc[tid];
  tvec[(size_t)(bb * 4 + 0) * NFF + tid] = a0 + bias;
  tvec[(size_t)(bb * 4 + 1) * NFF + tid] = a1 + bias;
  tvec[(size_t)(bb * 4 + 2) * NFF + tid] = a2 + bias;
  tvec[(size_t)(bb * 4 + 3) * NFF + tid] = a3 + bias;
}

// ---------------- gx = history(f32) @ W_ih^T + b_ih, output bf16 (NM x 1536) ----------------
__global__ __launch_bounds__(256) void k_gemm_gx(const float* __restrict__ Af,
                                                 const unsigned short* __restrict__ Bpk,
                                                 const float* __restrict__ bih,
                                                 unsigned short* __restrict__ gx){
  __shared__ unsigned short As[128 * 64];
  int tid = threadIdx.x; int lane = tid & 63; int wid = tid >> 6;
  int wm = wid >> 1, wn = wid & 1;
  int Nb = blockIdx.x, Mb = blockIdx.y;
  const float* Abase = Af + (size_t)Mb * 128 * ND;
  const short8v* Bp = (const short8v*)Bpk;
  f32x4 acc[4][4];
  #pragma unroll
  for (int i = 0; i < 4; ++i)
    #pragma unroll
    for (int j = 0; j < 4; ++j) acc[i][j] = (f32x4){0.f, 0.f, 0.f, 0.f};

  for (int kc = 0; kc < 8; ++kc){
    __syncthreads();
    #pragma unroll
    for (int pass = 0; pass < 4; ++pass){
      int idx = pass * 256 + tid; int r = idx >> 3, ch = idx & 7;
      const float* src = Abase + (size_t)r * ND + kc * 64 + ch * 8;
      float4 f0 = *(const float4*)src;
      float4 f1 = *(const float4*)(src + 4);
      uint4 v;
      v.x = (unsigned)f2bf(f0.x) | ((unsigned)f2bf(f0.y) << 16);
      v.y = (unsigned)f2bf(f0.z) | ((unsigned)f2bf(f0.w) << 16);
      v.z = (unsigned)f2bf(f1.x) | ((unsigned)f2bf(f1.y) << 16);
      v.w = (unsigned)f2bf(f1.z) | ((unsigned)f2bf(f1.w) << 16);
      *(uint4*)&As[r * 64 + ch * 8] = v;
    }
    __syncthreads();
    #pragma unroll
    for (int i = 0; i < 2; ++i){
      short8v a[4];
      #pragma unroll
      for (int mt = 0; mt < 4; ++mt)
        a[mt] = *(const short8v*)&As[(wm * 64 + mt * 16 + (lane & 15)) * 64 + i * 32 + (lane >> 4) * 8];
      #pragma unroll
      for (int nt = 0; nt < 4; ++nt){
        short8v b = Bp[((size_t)(Nb * 8 + wn * 4 + nt) * 16 + (kc * 2 + i)) * 64 + lane];
        #pragma unroll
        for (int mt = 0; mt < 4; ++mt)
          acc[mt][nt] = __builtin_amdgcn_mfma_f32_16x16x32_bf16(a[mt], b, acc[mt][nt], 0, 0, 0);
      }
    }
  }
  #pragma unroll
  for (int mt = 0; mt < 4; ++mt){
    #pragma unroll
    for (int nt = 0; nt < 4; ++nt){
      int gcol = Nb * 128 + wn * 64 + nt * 16 + (lane & 15);
      float bv = bih[gcol];
      #pragma unroll
      for (int r = 0; r < 4; ++r){
        int grow = Mb * 128 + wm * 64 + mt * 16 + (lane >> 4) * 4 + r;
        gx[(size_t)grow * NG + gcol] = f2bf(acc[mt][nt][r] + bv);
      }
    }
  }
}

// ---------------- GRU recurrence v7 ----------------
// Proven round-4 protocol (relaxed agent atomics) with the flag-publish chain minimized:
//   - gx prefetch AFTER the flag store (was inside the pre-flag vmcnt drain!)
//   - LDS-transpose staging -> ONE 8B coherent store per thread (was 4x4B)
//   - all-wave poll, no barrier between poll and reload
__global__ __launch_bounds__(512, 1) void k_gru7(const unsigned short* __restrict__ gx,
                                                 const unsigned short* __restrict__ Wpk,
                                                 const float* __restrict__ bhh,
                                                 unsigned short* __restrict__ gout,
                                                 unsigned long long* __restrict__ hx,  // [2][1024*128] u64
                                                 int* __restrict__ flags){             // [GRU_G*32] monotonic
  __shared__ unsigned short hbuf[2][16 * 512];   // [parity][16 k-frags of 1KB]
  __shared__ unsigned short hstg[16][136];       // block h-slice transpose staging (+pad)
  int tid = threadIdx.x; int lane = tid & 63; int nh = tid >> 6;   // wave 0..7
  int bid = blockIdx.x; int g = bid & 63; int s = bid >> 6;        // group, slice
  int colg = lane & 15;
  int rowg = lane >> 4;
  int c_h = s * 128 + nh * 16 + colg;   // this lane's h column
  int b0 = g * 16;                      // group batch base
  int* gfl = flags + g * 32;            // this group's 32 wave-flags

  for (int i = tid; i < 16 * 512; i += 512) hbuf[0][i] = 0;

  // resident W_hh B-fragments: 3 gate tiles x 16 k-frags = 192 regs
  short8v wf[3][16];
  const short8v* Wp = (const short8v*)Wpk;
  #pragma unroll
  for (int gg = 0; gg < 3; ++gg){
    int ntile = gg * 32 + s * 8 + nh;
    #pragma unroll
    for (int kk = 0; kk < 16; ++kk)
      wf[gg][kk] = Wp[((size_t)ntile * 16 + kk) * 64 + lane];
  }
  float bR = bhh[c_h], bZ = bhh[512 + c_h], bN = bhh[1024 + c_h];
  float hreg[4] = {0.f, 0.f, 0.f, 0.f};

  // writer mapping: thread -> one u64 (4 cols) of this block's h-slice
  int wbat = tid >> 5;            // 0..15
  int wc4  = tid & 31;            // 0..31 (4-col chunk within 128)

  // preload gx for t=0
  unsigned short cxr[4], cxz[4], cxn[4];
  #pragma unroll
  for (int r = 0; r < 4; ++r){
    const unsigned short* gp = gx + ((size_t)(b0 + rowg * 4 + r) * NS + 0) * NG;
    cxr[r] = gp[c_h]; cxz[r] = gp[512 + c_h]; cxn[r] = gp[1024 + c_h];
  }
  __syncthreads();

  #pragma unroll 1
  for (int t = 0; t < NS; ++t){
    int par = t & 1;
    const unsigned short* hr = hbuf[par];
    // gh = h @ Whh_slice^T
    f32x4 acc0 = (f32x4){0.f,0.f,0.f,0.f}, acc1 = acc0, acc2 = acc0;
    #pragma unroll
    for (int kc = 0; kc < 16; ++kc){
      short8v a = *(const short8v*)&hr[kc * 512 + lane * 8];
      acc0 = __builtin_amdgcn_mfma_f32_16x16x32_bf16(a, wf[0][kc], acc0, 0, 0, 0);
      acc1 = __builtin_amdgcn_mfma_f32_16x16x32_bf16(a, wf[1][kc], acc1, 0, 0, 0);
      acc2 = __builtin_amdgcn_mfma_f32_16x16x32_bf16(a, wf[2][kc], acc2, 0, 0, 0);
    }
    // activations; h kept in f32 regs across steps
    unsigned short hnew[4];
    #pragma unroll
    for (int r = 0; r < 4; ++r){
      float rr = sigm(bf2f(cxr[r]) + acc0[r] + bR);
      float zz = sigm(bf2f(cxz[r]) + acc1[r] + bZ);
      float nn = tanhfast(bf2f(cxn[r]) + rr * (acc2[r] + bN));
      float h = nn + zz * (hreg[r] - nn);
      hreg[r] = h;
      hnew[r] = f2bf(h);
    }

    if (t + 1 < NS){
      unsigned long long* hxp = hx + (size_t)par * (1024 * 128);
      // transpose-stage this block's 16x128 h-slice in LDS
      #pragma unroll
      for (int r = 0; r < 4; ++r) hstg[rowg * 4 + r][nh * 16 + colg] = hnew[r];
      __syncthreads();   // Bstg: slice staged
      // ONE 8B coherent store per thread
      {
        unsigned long long v8 = *(const unsigned long long*)&hstg[wbat][wc4 * 4];
        __hip_atomic_store(&hxp[(size_t)(b0 + wbat) * 128 + s * 32 + wc4], v8,
                           __ATOMIC_RELAXED, __HIP_MEMORY_SCOPE_AGENT);
      }
      // per-wave drain of the single coherent store, then flag (publish ASAP)
      asm volatile("s_waitcnt vmcnt(0)" ::: "memory");
      if (lane == 0)
        __hip_atomic_store(&gfl[s * 8 + nh], t + 1, __ATOMIC_RELAXED, __HIP_MEMORY_SCOPE_AGENT);
      // gout stores AFTER the flag (off the publish path)
      #pragma unroll
      for (int r = 0; r < 4; ++r)
        gout[((size_t)(b0 + rowg * 4 + r) * NS + t) * ND + c_h] = hnew[r];
      // gx prefetch for t+1 AFTER the flag -> overlaps poll + reload
      #pragma unroll
      for (int r = 0; r < 4; ++r){
        const unsigned short* gp = gx + ((size_t)(b0 + rowg * 4 + r) * NS + (t + 1)) * NG;
        cxr[r] = gp[c_h]; cxz[r] = gp[512 + c_h]; cxn[r] = gp[1024 + c_h];
      }
      // all-wave poll of the 32 wave-flags
      {
        int need = t + 1; int fv;
        do {
          fv = (lane < 32) ? __hip_atomic_load(&gfl[lane], __ATOMIC_RELAXED, __HIP_MEMORY_SCOPE_AGENT) : need;
        } while (!__all(fv >= need));
      }
      // reload full h_t into other-parity LDS in MFMA A-frag layout
      unsigned short* hw = hbuf[par ^ 1];
      #pragma unroll
      for (int q = 0; q < 2; ++q){
        int kc = q * 8 + nh;
        size_t base = (size_t)(b0 + (lane & 15)) * 128 + kc * 8 + (lane >> 4) * 2;
        unsigned long long u0 = __hip_atomic_load(&hxp[base],     __ATOMIC_RELAXED, __HIP_MEMORY_SCOPE_AGENT);
        unsigned long long u1 = __hip_atomic_load(&hxp[base + 1], __ATOMIC_RELAXED, __HIP_MEMORY_SCOPE_AGENT);
        unsigned long long tmp[2] = {u0, u1};
        *(uint4*)&hw[kc * 512 + lane * 8] = *(const uint4*)tmp;
      }
      __syncthreads();   // LDS h ready for next step
    } else {
      #pragma unroll
      for (int r = 0; r < 4; ++r)
        gout[((size_t)(b0 + rowg * 4 + r) * NS + t) * ND + c_h] = hnew[r];
    }
  }
}

// ---------------- pre/GELU/scores fused GEMM: (NM x 512) @ Wg^T (256) ----------------
__global__ __launch_bounds__(512) void k_gemm_s4(const unsigned short* __restrict__ A,
                                                 const unsigned short* __restrict__ Bpk,
                                                 const float* __restrict__ tvec,
                                                 const float* __restrict__ Wsc,
                                                 const float* __restrict__ bsc,
                                                 float* __restrict__ scores){
  __shared__ unsigned short As[128 * 64];
  __shared__ float spart[4][128];
  int tid = threadIdx.x; int lane = tid & 63; int wid = tid >> 6;
  int wm = wid >> 2, wn = wid & 3;
  int Mb = blockIdx.x;
  const unsigned short* Abase = A + (size_t)Mb * 128 * ND;
  const short8v* Bp = (const short8v*)Bpk;
  f32x4 acc[4][4];
  #pragma unroll
  for (int i = 0; i < 4; ++i)
    #pragma unroll
    for (int j = 0; j < 4; ++j) acc[i][j] = (f32x4){0.f, 0.f, 0.f, 0.f};

  for (int kc = 0; kc < 8; ++kc){
    __syncthreads();
    #pragma unroll
    for (int pass = 0; pass < 2; ++pass){
      int idx = pass * 512 + tid; int r = idx >> 3, ch = idx & 7;
      uint4 v = *(const uint4*)(Abase + (size_t)r * ND + kc * 64 + ch * 8);
      *(uint4*)&As[r * 64 + ch * 8] = v;
    }
    __syncthreads();
    #pragma unroll
    for (int i = 0; i < 2; ++i){
      short8v a[4];
      #pragma unroll
      for (int mt = 0; mt < 4; ++mt)
        a[mt] = *(const short8v*)&As[(wm * 64 + mt * 16 + (lane & 15)) * 64 + i * 32 + (lane >> 4) * 8];
      #pragma unroll
      for (int nt = 0; nt < 4; ++nt){
        short8v b = Bp[((size_t)(wn * 4 + nt) * 16 + (kc * 2 + i)) * 64 + lane];
        #pragma unroll
        for (int mt = 0; mt < 4; ++mt)
          acc[mt][nt] = __builtin_amdgcn_mfma_f32_16x16x32_bf16(a[mt], b, acc[mt][nt], 0, 0, 0);
      }
    }
  }
  #pragma unroll
  for (int mt = 0; mt < 4; ++mt){
    #pragma unroll
    for (int r = 0; r < 4; ++r){
      int rowl = wm * 64 + mt * 16 + (lane >> 4) * 4 + r;
      unsigned grow = (unsigned)(Mb * 128 + rowl);
      unsigned bidx = grow / 200u;
      float rowsum = 0.f;
      #pragma unroll
      for (int nt = 0; nt < 4; ++nt){
        int gcol = wn * 64 + nt * 16 + (lane & 15);
        float pre = acc[mt][nt][r] + tvec[(size_t)bidx * NFF + gcol];
        float g = 0.5f * pre * (1.f + erff(pre * 0.70710678118654752f));
        rowsum += g * Wsc[gcol];
      }
      rowsum += __shfl_xor(rowsum, 1, 64);
      rowsum += __shfl_xor(rowsum, 2, 64);
      rowsum += __shfl_xor(rowsum, 4, 64);
      rowsum += __shfl_xor(rowsum, 8, 64);
      if ((lane & 15) == 0) spart[wn][rowl] = rowsum;
    }
  }
  __syncthreads();
  if (tid < 128){
    float s = spart[0][tid] + spart[1][tid] + spart[2][tid] + spart[3][tid] + bsc[0];
    scores[(size_t)Mb * 128 + tid] = s;
  }
}

// ---------------- softmax over S + weighted pool + concat output ----------------
__global__ void k_out(const float* __restrict__ scores, const unsigned short* __restrict__ gout,
                      const float* __restrict__ target, float* __restrict__ out){
  int b = blockIdx.x; int tid = threadIdx.x;
  __shared__ float sw[NS];
  __shared__ float red[4];
  float v = (tid < NS) ? scores[(size_t)b * NS + tid] : -3.0e38f;
  float m = v;
  #pragma unroll
  for (int off = 32; off >= 1; off >>= 1) m = fmaxf(m, __shfl_xor(m, off, 64));
  if ((tid & 63) == 0) red[tid >> 6] = m;
  __syncthreads();
  m = fmaxf(fmaxf(red[0], red[1]), fmaxf(red[2], red[3]));
  float e = (tid < NS) ? __expf(v - m) : 0.f;
  if (tid < NS) sw[tid] = e;
  float su = e;
  #pragma unroll
  for (int off = 32; off >= 1; off >>= 1) su += __shfl_xor(su, off, 64);
  __syncthreads();
  if ((tid & 63) == 0) red[tid >> 6] = su;
  __syncthreads();
  float inv = 1.f / (red[0] + red[1] + red[2] + red[3]);
  int d0 = tid * 2;
  float a0 = 0.f, a1 = 0.f;
  const unsigned short* gbase = gout + (size_t)b * NS * ND + d0;
  for (int s = 0; s < NS; ++s){
    unsigned u = *(const unsigned*)(gbase + (size_t)s * ND);
    float wgt = sw[s];
    a0 += wgt * bf2f((unsigned short)(u & 0xffffu));
    a1 += wgt * bf2f((unsigned short)(u >> 16));
  }
  out[(size_t)b * 1024 + d0] = a0 * inv;
  out[(size_t)b * 1024 + d0 + 1] = a1 * inv;
  float2 tv = *(const float2*)(target + (size_t)b * ND + d0);
  out[(size_t)b * 1024 + 512 + d0] = tv.x;
  out[(size_t)b * 1024 + 512 + d0 + 1] = tv.y;
}

extern "C" void kernel_launch(void* const* d_in, const int* in_sizes, int n_in,
                              void* d_out, int out_size, void* d_ws, size_t ws_size,
                              hipStream_t stream) {
  const float* target  = (const float*)d_in[0];
  const float* history = (const float*)d_in[1];
  const float* W_ih    = (const float*)d_in[2];
  const float* W_hh    = (const float*)d_in[3];
  const float* b_ih    = (const float*)d_in[4];
  const float* b_hh    = (const float*)d_in[5];
  const float* W_fc    = (const float*)d_in[6];
  const float* b_fc    = (const float*)d_in[7];
  const float* W_sc    = (const float*)d_in[8];
  const float* b_sc    = (const float*)d_in[9];

  char* ws = (char*)d_ws;
  size_t off = 0;
  unsigned short* gx     = (unsigned short*)(ws + off); off += 629145600ull;  // NM*1536 bf16
  unsigned short* gout   = (unsigned short*)(ws + off); off += 209715200ull;  // NM*512 bf16
  unsigned short* wih_pk = (unsigned short*)(ws + off); off += 1572864ull;
  unsigned short* whh_pk = (unsigned short*)(ws + off); off += 1572864ull;
  unsigned short* wg_pk  = (unsigned short*)(ws + off); off += 262144ull;
  float*          tvec   = (float*)(ws + off);          off += 1048576ull;
  float*          scores = (float*)(ws + off);          off += 819200ull;
  unsigned long long* hx = (unsigned long long*)(ws + off); off += 2097152ull; // [2][1024*128] u64
  int*            flags  = (int*)(ws + off);             off += 8192ull;        // [64*32] monotonic
  if (ws_size < off) return;
  float* outp = (float*)d_out;

  (void)hipMemsetAsync(flags, 0, GRU_G * 32 * sizeof(int), stream);
  k_prepack<<<384, 256, 0, stream>>>(W_ih, wih_pk, 512, 0, 96);
  k_prepack<<<384, 256, 0, stream>>>(W_hh, whh_pk, 512, 0, 96);
  k_prepack<<<64, 256, 0, stream>>>(W_fc, wg_pk, 1024, 0, 16);
  k_tvec<<<256, 256, 0, stream>>>(target, W_fc, b_fc, tvec);
  k_gemm_gx<<<dim3(12, 1600), 256, 0, stream>>>(history, wih_pk, b_ih, gx);
  k_gru7<<<256, 512, 0, stream>>>(gx, whh_pk, b_hh, gout, hx, flags);
  k_gemm_s4<<<1600, 512, 0, stream>>>(gout, wg_pk, tvec, W_sc, b_sc, scores);
  k_out<<<1024, 256, 0, stream>>>(scores, gout, target, outp);
}